// Round 1
// baseline (398.678 us; speedup 1.0000x reference)
//
#include <hip/hip_runtime.h>

// Shapes: B=32, N=32, HID=256, H=8, D=32, A=256
// edges e = (b*32+l)*32+r, 32768 total.

__device__ __forceinline__ float bf2f(unsigned short u) {
  union { unsigned int i; float f; } c; c.i = ((unsigned int)u) << 16; return c.f;
}
__device__ __forceinline__ unsigned short f2bf(float f) {
  unsigned int x = __float_as_uint(f);
  unsigned int r = x + 0x7fffu + ((x >> 16) & 1u);  // RNE
  return (unsigned short)(r >> 16);
}

// ---------------------------------------------------------------------------
// Kernel 1: per-node projections. qlin = h@Wq+bq, vlin = h@Wv+bv,
// krow = h@Wk[0:256], kcol = h@Wk[256:512].  1024 rows of 256.
// ---------------------------------------------------------------------------
__global__ __launch_bounds__(256) void k_small(
    const float* __restrict__ hidden, const float* __restrict__ Wq,
    const float* __restrict__ bq, const float* __restrict__ Wk,
    const float* __restrict__ Wv, const float* __restrict__ bv,
    float* __restrict__ qlin, float* __restrict__ vlin,
    float* __restrict__ krow, float* __restrict__ kcol)
{
  __shared__ float hs[4][256];
  const int j = threadIdx.x;
  const int row0 = blockIdx.x * 4;
#pragma unroll
  for (int m = 0; m < 4; ++m) hs[m][j] = hidden[(size_t)(row0 + m) * 256 + j];
  __syncthreads();
  float aq[4] = {0,0,0,0}, a1[4] = {0,0,0,0}, a2[4] = {0,0,0,0}, av[4] = {0,0,0,0};
  for (int i = 0; i < 256; ++i) {
    float wq = Wq[i * 256 + j];
    float w1 = Wk[i * 256 + j];
    float w2 = Wk[(256 + i) * 256 + j];
    float wv = Wv[i * 256 + j];
#pragma unroll
    for (int m = 0; m < 4; ++m) {
      float s = hs[m][i];
      aq[m] = fmaf(s, wq, aq[m]);
      a1[m] = fmaf(s, w1, a1[m]);
      a2[m] = fmaf(s, w2, a2[m]);
      av[m] = fmaf(s, wv, av[m]);
    }
  }
  float bqv = bq[j], bvv = bv[j];
#pragma unroll
  for (int m = 0; m < 4; ++m) {
    size_t o = (size_t)(row0 + m) * 256 + j;
    qlin[o] = aq[m] + bqv;
    vlin[o] = av[m] + bvv;
    krow[o] = a1[m];
    kcol[o] = a2[m];
  }
}

// ---------------------------------------------------------------------------
// Kernel 2: K projection per edge.
// Kall[e][j] = bf16( structure[e]@Wk3 + krow[b,l] + kcol[b,r] + bk )
// One block per (b,l): 32 edges. thread = (rg: 4 rows, cg: 8 cols).
// ---------------------------------------------------------------------------
__global__ __launch_bounds__(256) void k_kproj(
    const float* __restrict__ structure, const float* __restrict__ Wk,
    const float* __restrict__ bk, const float* __restrict__ krow,
    const float* __restrict__ kcol, unsigned short* __restrict__ Kall)
{
  __shared__ float s[32][256];
  const int t = threadIdx.x;
  const int bl = blockIdx.x;
  const int b = bl >> 5;
  const float* sp = structure + (size_t)bl * (32 * 256);
#pragma unroll
  for (int u = 0; u < 8; ++u) {
    int idx = (u * 256 + t) * 4;
    float4 v4 = *(const float4*)(sp + idx);
    *(float4*)&s[idx >> 8][idx & 255] = v4;
  }
  __syncthreads();
  const int rg = t >> 5;
  const int cg = t & 31;
  float acc[4][8];
#pragma unroll
  for (int a = 0; a < 4; ++a)
#pragma unroll
    for (int c = 0; c < 8; ++c) acc[a][c] = 0.f;
  const float* wb = Wk + 512 * 256 + cg * 8;
  for (int i = 0; i < 256; ++i) {
    float4 w0 = *(const float4*)(wb + i * 256);
    float4 w1 = *(const float4*)(wb + i * 256 + 4);
#pragma unroll
    for (int a = 0; a < 4; ++a) {
      float sv = s[rg * 4 + a][i];
      acc[a][0] = fmaf(sv, w0.x, acc[a][0]);
      acc[a][1] = fmaf(sv, w0.y, acc[a][1]);
      acc[a][2] = fmaf(sv, w0.z, acc[a][2]);
      acc[a][3] = fmaf(sv, w0.w, acc[a][3]);
      acc[a][4] = fmaf(sv, w1.x, acc[a][4]);
      acc[a][5] = fmaf(sv, w1.y, acc[a][5]);
      acc[a][6] = fmaf(sv, w1.z, acc[a][6]);
      acc[a][7] = fmaf(sv, w1.w, acc[a][7]);
    }
  }
  float4 bk0 = *(const float4*)(bk + cg * 8);
  float4 bk1 = *(const float4*)(bk + cg * 8 + 4);
  float4 kr0 = *(const float4*)(krow + (size_t)bl * 256 + cg * 8);
  float4 kr1 = *(const float4*)(krow + (size_t)bl * 256 + cg * 8 + 4);
#pragma unroll
  for (int a = 0; a < 4; ++a) {
    int r = rg * 4 + a;
    const float* kcp = kcol + (size_t)(b * 32 + r) * 256 + cg * 8;
    float4 kc0 = *(const float4*)kcp;
    float4 kc1 = *(const float4*)(kcp + 4);
    float o0 = acc[a][0] + bk0.x + kr0.x + kc0.x;
    float o1 = acc[a][1] + bk0.y + kr0.y + kc0.y;
    float o2 = acc[a][2] + bk0.z + kr0.z + kc0.z;
    float o3 = acc[a][3] + bk0.w + kr0.w + kc0.w;
    float o4 = acc[a][4] + bk1.x + kr1.x + kc1.x;
    float o5 = acc[a][5] + bk1.y + kr1.y + kc1.y;
    float o6 = acc[a][6] + bk1.z + kr1.z + kc1.z;
    float o7 = acc[a][7] + bk1.w + kr1.w + kc1.w;
    uint4 pk;
    pk.x = (unsigned int)f2bf(o0) | ((unsigned int)f2bf(o1) << 16);
    pk.y = (unsigned int)f2bf(o2) | ((unsigned int)f2bf(o3) << 16);
    pk.z = (unsigned int)f2bf(o4) | ((unsigned int)f2bf(o5) << 16);
    pk.w = (unsigned int)f2bf(o6) | ((unsigned int)f2bf(o7) << 16);
    *(uint4*)&Kall[((size_t)bl * 32 + r) * 256 + cg * 8] = pk;
  }
}

// ---------------------------------------------------------------------------
// Kernel 3: fused per-(b,l) attention + output projection + residual + LN.
// ---------------------------------------------------------------------------
__global__ __launch_bounds__(256, 2) void k_attn(
    const float* __restrict__ qlin, const float* __restrict__ vlin,
    const unsigned short* __restrict__ Kall,
    const float* __restrict__ triplet, const float* __restrict__ mask,
    const float* __restrict__ Wtq, const float* __restrict__ btq,
    const float* __restrict__ Wtk, const float* __restrict__ btk,
    const float* __restrict__ Wo, const float* __restrict__ bo,
    const float* __restrict__ structure,
    const float* __restrict__ gamma, const float* __restrict__ beta,
    float* __restrict__ out)
{
  __shared__ __align__(16) char smem[72736];
  unsigned short* qs  = (unsigned short*)smem;            // [32][260] bf16
  unsigned short* vs  = (unsigned short*)(smem + 16640);  // [32][256] bf16
  unsigned short* cxs = (unsigned short*)(smem + 33024);  // [32][256] bf16
  float* Tb  = (float*)(smem + 49408);  // [32][34]
  float* tqb = (float*)(smem + 53760);  // [32][34]
  float* tkb = (float*)(smem + 58112);  // [32][34]
  float* wtq = (float*)(smem + 62464);  // [32][32]
  float* wtk = (float*)(smem + 66560);  // [32][32]
  float* keb = (float*)(smem + 70656);  // [256]
  float* pb  = (float*)(smem + 71680);  // [8][33]
  float* xb  = (float*)smem;            // [32][256] fp32, phase 2 (overlays qs/vs)

  const int t = threadIdx.x;
  const int bl = blockIdx.x;
  const int b = bl >> 5;

  // preload q, v (as bf16) and the tiny triplet weights
  for (int n = 0; n < 32; ++n) {
    qs[n * 260 + t] = f2bf(qlin[((size_t)b * 32 + n) * 256 + t]);
    vs[n * 256 + t] = f2bf(vlin[((size_t)b * 32 + n) * 256 + t]);
  }
  *(float4*)&wtq[t * 4] = *(const float4*)(Wtq + t * 4);
  *(float4*)&wtk[t * 4] = *(const float4*)(Wtk + t * 4);
  __syncthreads();

  const int h5 = t >> 5, n5 = t & 31;       // scores mapping
  const int nt = t >> 3, d0 = (t & 7) * 4;  // tq/tk mapping
  float4 btqv = *(const float4*)(btq + d0);
  float4 btkv = *(const float4*)(btk + d0);

  for (int r = 0; r < 32; ++r) {
    const size_t e = (size_t)bl * 32 + r;
    // stage triplet tile [32n][32d] and k-edge
    float4 tv = *(const float4*)(triplet + e * 1024 + t * 4);
    Tb[nt * 34 + d0 + 0] = tv.x;
    Tb[nt * 34 + d0 + 1] = tv.y;
    Tb[nt * 34 + d0 + 2] = tv.z;
    Tb[nt * 34 + d0 + 3] = tv.w;
    keb[t] = bf2f(Kall[e * 256 + t]);
    __syncthreads();

    // tq/tk: thread computes tq[nt][d0..d0+3], tk[nt][d0..d0+3]
    {
      float a0 = btqv.x, a1 = btqv.y, a2 = btqv.z, a3 = btqv.w;
      float c0 = btkv.x, c1 = btkv.y, c2 = btkv.z, c3 = btkv.w;
#pragma unroll 8
      for (int i = 0; i < 32; ++i) {
        float sv = Tb[nt * 34 + i];
        float4 wq4 = *(const float4*)&wtq[i * 32 + d0];
        float4 wk4 = *(const float4*)&wtk[i * 32 + d0];
        a0 = fmaf(sv, wq4.x, a0); a1 = fmaf(sv, wq4.y, a1);
        a2 = fmaf(sv, wq4.z, a2); a3 = fmaf(sv, wq4.w, a3);
        c0 = fmaf(sv, wk4.x, c0); c1 = fmaf(sv, wk4.y, c1);
        c2 = fmaf(sv, wk4.z, c2); c3 = fmaf(sv, wk4.w, c3);
      }
      tqb[nt * 34 + d0 + 0] = a0; tqb[nt * 34 + d0 + 1] = a1;
      tqb[nt * 34 + d0 + 2] = a2; tqb[nt * 34 + d0 + 3] = a3;
      tkb[nt * 34 + d0 + 0] = c0; tkb[nt * 34 + d0 + 1] = c1;
      tkb[nt * 34 + d0 + 2] = c2; tkb[nt * 34 + d0 + 3] = c3;
    }
    __syncthreads();

    // scores + softmax: thread = (h5, n5)
    {
      float sc = 0.f;
      const unsigned short* qrow = qs + n5 * 260 + h5 * 32;
#pragma unroll
      for (int dc = 0; dc < 32; dc += 4) {
        float4 ke4 = *(const float4*)&keb[h5 * 32 + dc];
        float2 tq0 = *(const float2*)&tqb[n5 * 34 + dc];
        float2 tq1 = *(const float2*)&tqb[n5 * 34 + dc + 2];
        float2 tk0 = *(const float2*)&tkb[n5 * 34 + dc];
        float2 tk1 = *(const float2*)&tkb[n5 * 34 + dc + 2];
        uint2 qr = *(const uint2*)(qrow + dc);
        float q0 = bf2f((unsigned short)(qr.x & 0xffff));
        float q1 = bf2f((unsigned short)(qr.x >> 16));
        float q2 = bf2f((unsigned short)(qr.y & 0xffff));
        float q3 = bf2f((unsigned short)(qr.y >> 16));
        sc = fmaf(q0, ke4.x + tq0.x, fmaf(ke4.x, tk0.x, sc));
        sc = fmaf(q1, ke4.y + tq0.y, fmaf(ke4.y, tk0.y, sc));
        sc = fmaf(q2, ke4.z + tq1.x, fmaf(ke4.z, tk1.x, sc));
        sc = fmaf(q3, ke4.w + tq1.y, fmaf(ke4.w, tk1.y, sc));
      }
      sc = sc * 0.17677669529663687f + mask[e * 32 + n5];
      float mx = sc;
#pragma unroll
      for (int mm = 16; mm >= 1; mm >>= 1) mx = fmaxf(mx, __shfl_xor(mx, mm, 64));
      float p = __expf(sc - mx);
      float sum = p;
#pragma unroll
      for (int mm = 16; mm >= 1; mm >>= 1) sum += __shfl_xor(sum, mm, 64);
      pb[h5 * 33 + n5] = p / sum;
    }
    __syncthreads();

    // ctx: thread = output column j = t (h = t>>5)
    {
      float acc = 0.f;
      const float* prow = pb + h5 * 33;
#pragma unroll 8
      for (int n = 0; n < 32; ++n)
        acc = fmaf(prow[n], bf2f(vs[n * 256 + t]), acc);
      cxs[r * 256 + t] = f2bf(acc);
    }
  }
  __syncthreads();

  // phase 2: out = cxs@Wo + bo + structure; store fp32 rows to xb
  {
    const int rg = t >> 5, cg = t & 31;
    float acc[4][8];
#pragma unroll
    for (int a = 0; a < 4; ++a)
#pragma unroll
      for (int c = 0; c < 8; ++c) acc[a][c] = 0.f;
    const float* wb = Wo + cg * 8;
    for (int i = 0; i < 256; ++i) {
      float4 w0 = *(const float4*)(wb + i * 256);
      float4 w1 = *(const float4*)(wb + i * 256 + 4);
#pragma unroll
      for (int a = 0; a < 4; ++a) {
        float cv = bf2f(cxs[(rg * 4 + a) * 256 + i]);
        acc[a][0] = fmaf(cv, w0.x, acc[a][0]);
        acc[a][1] = fmaf(cv, w0.y, acc[a][1]);
        acc[a][2] = fmaf(cv, w0.z, acc[a][2]);
        acc[a][3] = fmaf(cv, w0.w, acc[a][3]);
        acc[a][4] = fmaf(cv, w1.x, acc[a][4]);
        acc[a][5] = fmaf(cv, w1.y, acc[a][5]);
        acc[a][6] = fmaf(cv, w1.z, acc[a][6]);
        acc[a][7] = fmaf(cv, w1.w, acc[a][7]);
      }
    }
    float4 bo0 = *(const float4*)(bo + cg * 8);
    float4 bo1 = *(const float4*)(bo + cg * 8 + 4);
#pragma unroll
    for (int a = 0; a < 4; ++a) {
      int r = rg * 4 + a;
      const float* sp2 = structure + ((size_t)bl * 32 + r) * 256 + cg * 8;
      float4 s0 = *(const float4*)sp2;
      float4 s1 = *(const float4*)(sp2 + 4);
      float* xr = xb + r * 256 + cg * 8;
      xr[0] = acc[a][0] + bo0.x + s0.x;
      xr[1] = acc[a][1] + bo0.y + s0.y;
      xr[2] = acc[a][2] + bo0.z + s0.z;
      xr[3] = acc[a][3] + bo0.w + s0.w;
      xr[4] = acc[a][4] + bo1.x + s1.x;
      xr[5] = acc[a][5] + bo1.y + s1.y;
      xr[6] = acc[a][6] + bo1.z + s1.z;
      xr[7] = acc[a][7] + bo1.w + s1.w;
    }
  }
  __syncthreads();

  // LayerNorm: wave wv handles rows wv*8..wv*8+7; 64 lanes x 4 elems each
  {
    const int wv = t >> 6, lane = t & 63;
#pragma unroll
    for (int rr = 0; rr < 8; ++rr) {
      int r = wv * 8 + rr;
      float4 x4 = *(const float4*)&xb[r * 256 + lane * 4];
      float s1 = x4.x + x4.y + x4.z + x4.w;
      float s2 = fmaf(x4.x, x4.x, fmaf(x4.y, x4.y, fmaf(x4.z, x4.z, x4.w * x4.w)));
#pragma unroll
      for (int mm = 32; mm >= 1; mm >>= 1) {
        s1 += __shfl_xor(s1, mm, 64);
        s2 += __shfl_xor(s2, mm, 64);
      }
      float mu = s1 * (1.f / 256.f);
      float var = s2 * (1.f / 256.f) - mu * mu;
      float rstd = rsqrtf(var + 1e-5f);
      float4 g = *(const float4*)(gamma + lane * 4);
      float4 bt = *(const float4*)(beta + lane * 4);
      float4 o;
      o.x = (x4.x - mu) * rstd * g.x + bt.x;
      o.y = (x4.y - mu) * rstd * g.y + bt.y;
      o.z = (x4.z - mu) * rstd * g.z + bt.z;
      o.w = (x4.w - mu) * rstd * g.w + bt.w;
      *(float4*)&out[((size_t)bl * 32 + r) * 256 + lane * 4] = o;
    }
  }
}

extern "C" void kernel_launch(void* const* d_in, const int* in_sizes, int n_in,
                              void* d_out, int out_size, void* d_ws, size_t ws_size,
                              hipStream_t stream) {
  const float* hidden    = (const float*)d_in[0];
  const float* structure = (const float*)d_in[1];
  const float* triplet   = (const float*)d_in[2];
  const float* mask      = (const float*)d_in[3];
  const float* Wq  = (const float*)d_in[4];
  const float* bq  = (const float*)d_in[5];
  const float* Wk  = (const float*)d_in[6];
  const float* bk  = (const float*)d_in[7];
  const float* Wv  = (const float*)d_in[8];
  const float* bv  = (const float*)d_in[9];
  const float* Wo  = (const float*)d_in[10];
  const float* bo  = (const float*)d_in[11];
  const float* gamma = (const float*)d_in[12];
  const float* beta  = (const float*)d_in[13];
  const float* Wtq = (const float*)d_in[14];
  const float* btq = (const float*)d_in[15];
  const float* Wtk = (const float*)d_in[16];
  const float* btk = (const float*)d_in[17];
  float* out = (float*)d_out;

  float* qlin = (float*)d_ws;
  float* vlin = qlin + 262144;
  float* krow = vlin + 262144;
  float* kcol = krow + 262144;
  unsigned short* Kall = (unsigned short*)(kcol + 262144);  // [32768][256] bf16

  hipLaunchKernelGGL(k_small, dim3(256), dim3(256), 0, stream,
                     hidden, Wq, bq, Wk, Wv, bv, qlin, vlin, krow, kcol);
  hipLaunchKernelGGL(k_kproj, dim3(1024), dim3(256), 0, stream,
                     structure, Wk, bk, krow, kcol, Kall);
  hipLaunchKernelGGL(k_attn, dim3(1024), dim3(256), 0, stream,
                     qlin, vlin, Kall, triplet, mask, Wtq, btq, Wtk, btk,
                     Wo, bo, structure, gamma, beta, out);
}

// Round 5
// 226.734 us; speedup vs baseline: 1.7584x; 1.7584x over previous
//
#include <hip/hip_runtime.h>

// Shapes: B=32, N=32, HID=256, H=8, D=32, A=256. edges e=(b*32+l)*32+r.
// Workspace: 19.0 MB. Round-5 bisection: Wo GEMM reverted to VALU fp32
// (round-1-proven); kproj/tq-tk stay MFMA (errors there provably damped).

typedef __attribute__((ext_vector_type(8))) short bs8;     // 8 bf16 in 4 VGPRs
typedef __attribute__((ext_vector_type(16))) float fx16;   // 32x32 MFMA acc

union FB { unsigned short u[8]; uint4 q; bs8 v; };

__device__ __forceinline__ float bf2f(unsigned short u) {
  return __uint_as_float(((unsigned int)u) << 16);
}
__device__ __forceinline__ float2 bf2x(unsigned int p) {
  float2 r;
  r.x = __uint_as_float(p << 16);
  r.y = __uint_as_float(p & 0xffff0000u);
  return r;
}
__device__ __forceinline__ unsigned short f2bf(float f) {
  unsigned int x = __float_as_uint(f);
  unsigned int r = x + 0x7fffu + ((x >> 16) & 1u);  // RNE
  return (unsigned short)(r >> 16);
}

// ---------------------------------------------------------------------------
// prep: Wk3T[c][k] = bf16(Wk[512+k][c])
// ---------------------------------------------------------------------------
__global__ __launch_bounds__(256) void k_prep(
    const float* __restrict__ Wk, unsigned short* __restrict__ Wk3T) {
  const int c = blockIdx.x;
  const int t = threadIdx.x;
  Wk3T[c * 256 + t] = f2bf(Wk[(512 + t) * 256 + c]);
}

// ---------------------------------------------------------------------------
// k_small: per-node projections -> bf16 outputs.
// ---------------------------------------------------------------------------
__global__ __launch_bounds__(256) void k_small(
    const float* __restrict__ hidden, const float* __restrict__ Wq,
    const float* __restrict__ bq, const float* __restrict__ Wk,
    const float* __restrict__ Wv, const float* __restrict__ bv,
    unsigned short* __restrict__ qb, unsigned short* __restrict__ vb,
    unsigned short* __restrict__ krb, unsigned short* __restrict__ kcb)
{
  __shared__ float hs[4][256];
  const int j = threadIdx.x;
  const int row0 = blockIdx.x * 4;
#pragma unroll
  for (int m = 0; m < 4; ++m) hs[m][j] = hidden[(size_t)(row0 + m) * 256 + j];
  __syncthreads();
  float aq[4] = {0,0,0,0}, a1[4] = {0,0,0,0}, a2[4] = {0,0,0,0}, av[4] = {0,0,0,0};
  for (int i = 0; i < 256; ++i) {
    float wq = Wq[i * 256 + j];
    float w1 = Wk[i * 256 + j];
    float w2 = Wk[(256 + i) * 256 + j];
    float wv = Wv[i * 256 + j];
#pragma unroll
    for (int m = 0; m < 4; ++m) {
      float s = hs[m][i];
      aq[m] = fmaf(s, wq, aq[m]);
      a1[m] = fmaf(s, w1, a1[m]);
      a2[m] = fmaf(s, w2, a2[m]);
      av[m] = fmaf(s, wv, av[m]);
    }
  }
  float bqv = bq[j], bvv = bv[j];
#pragma unroll
  for (int m = 0; m < 4; ++m) {
    size_t o = (size_t)(row0 + m) * 256 + j;
    qb[o]  = f2bf(aq[m] + bqv);
    vb[o]  = f2bf(av[m] + bvv);
    krb[o] = f2bf(a1[m]);
    kcb[o] = f2bf(a2[m]);
  }
}

// ---------------------------------------------------------------------------
// k_kproj (MFMA 32x32): Kall[e][col] = bf16(structure[e]@Wk3 + krow + kcol + bk)
// ---------------------------------------------------------------------------
__global__ __launch_bounds__(256) void k_kproj(
    const float* __restrict__ structure, const unsigned short* __restrict__ Wk3T,
    const float* __restrict__ bk, const unsigned short* __restrict__ krb,
    const unsigned short* __restrict__ kcb, unsigned short* __restrict__ Kall)
{
  const int t = threadIdx.x, w = t >> 6, lane = t & 63;
  const int bl = blockIdx.x, b = bl >> 5;
  const int rowA = lane & 31, hh = lane >> 5;
  const int col0 = w * 64 + (lane & 31);
  const float* Ap = structure + (size_t)bl * 8192 + rowA * 256 + hh * 8;
  fx16 acc0, acc1;
#pragma unroll
  for (int j = 0; j < 16; ++j) { acc0[j] = 0.f; acc1[j] = 0.f; }
  for (int k0 = 0; k0 < 256; k0 += 16) {
    float4 a0 = *(const float4*)(Ap + k0);
    float4 a1 = *(const float4*)(Ap + k0 + 4);
    FB af;
    af.u[0] = f2bf(a0.x); af.u[1] = f2bf(a0.y); af.u[2] = f2bf(a0.z); af.u[3] = f2bf(a0.w);
    af.u[4] = f2bf(a1.x); af.u[5] = f2bf(a1.y); af.u[6] = f2bf(a1.z); af.u[7] = f2bf(a1.w);
    FB b0, b1;
    b0.q = *(const uint4*)(Wk3T + (size_t)col0 * 256 + k0 + hh * 8);
    b1.q = *(const uint4*)(Wk3T + (size_t)(col0 + 32) * 256 + k0 + hh * 8);
    acc0 = __builtin_amdgcn_mfma_f32_32x32x16_bf16(af.v, b0.v, acc0, 0, 0, 0);
    acc1 = __builtin_amdgcn_mfma_f32_32x32x16_bf16(af.v, b1.v, acc1, 0, 0, 0);
  }
  float bk0 = bk[col0], bk1 = bk[col0 + 32];
  float kr0 = bf2f(krb[(size_t)bl * 256 + col0]);
  float kr1 = bf2f(krb[(size_t)bl * 256 + col0 + 32]);
#pragma unroll
  for (int reg = 0; reg < 16; ++reg) {
    int r = (reg & 3) + 8 * (reg >> 2) + 4 * hh;
    const unsigned short* kcp = kcb + ((size_t)b * 32 + r) * 256;
    size_t o = ((size_t)bl * 32 + r) * 256;
    Kall[o + col0]      = f2bf(acc0[reg] + bk0 + kr0 + bf2f(kcp[col0]));
    Kall[o + col0 + 32] = f2bf(acc1[reg] + bk1 + kr1 + bf2f(kcp[col0 + 32]));
  }
}

// ---------------------------------------------------------------------------
// k_attn: per-(b,l) block, 4 waves, wave w owns edges r=w*8..w*8+7.
// Phase 1 (per-wave): tq/tk MFMA (fp32 LDS), scores, softmax, ctx in regs.
// Phase 2: ctx regs -> LDS; ctx@Wo via VALU fp32 (round-1-proven)
//   + bo + structure; LayerNorm -> out.
// ---------------------------------------------------------------------------
__global__ __launch_bounds__(256, 2) void k_attn(
    const unsigned short* __restrict__ qb, const unsigned short* __restrict__ vb,
    const unsigned short* __restrict__ Kall,
    const float* __restrict__ triplet, const float* __restrict__ mask,
    const float* __restrict__ Wtq, const float* __restrict__ btq,
    const float* __restrict__ Wtk, const float* __restrict__ btk,
    const float* __restrict__ Wo, const float* __restrict__ bo,
    const float* __restrict__ structure,
    const float* __restrict__ gamma, const float* __restrict__ beta,
    float* __restrict__ out)
{
  __shared__ __align__(16) char smem[76224];
  unsigned short* qs = (unsigned short*)smem;            // [32][260]
  unsigned short* vs = (unsigned short*)(smem + 16640);  // [32][256]
  float* tqb = (float*)(smem + 33024);                   // [4][32][36]
  float* tkb = (float*)(smem + 51456);                   // [4][32][36]
  unsigned short* Kbb = (unsigned short*)(smem + 69888); // [4][264]
  float* pbb = (float*)(smem + 72000);                   // [4][8][33]

  const int t = threadIdx.x, w = t >> 6, lane = t & 63;
  const int bl = blockIdx.x, b = bl >> 5;
  const int n_l = lane & 31, hh = lane >> 5;

  for (int n = 0; n < 32; ++n) {
    qs[n * 260 + t] = qb[((size_t)b * 32 + n) * 256 + t];
    vs[n * 256 + t] = vb[((size_t)b * 32 + n) * 256 + t];
  }
  FB bqf[2], bkf[2];
#pragma unroll
  for (int s = 0; s < 2; ++s)
#pragma unroll
    for (int e2 = 0; e2 < 8; ++e2) {
      int k = s * 16 + hh * 8 + e2;
      bqf[s].u[e2] = f2bf(Wtq[k * 32 + n_l]);
      bkf[s].u[e2] = f2bf(Wtk[k * 32 + n_l]);
    }
  const float btqc = btq[n_l], btkc = btk[n_l];
  __syncthreads();

  const int j0 = lane * 4, hj = lane >> 3;
  float* tqw = tqb + w * (32 * 36);
  float* tkw = tkb + w * (32 * 36);
  unsigned short* Kw = Kbb + w * 264;
  float* pw = pbb + w * (8 * 33);
  unsigned int ctxr[8][2];

  for (int i = 0; i < 8; ++i) {
    const int r = w * 8 + i;
    const size_t e = (size_t)bl * 32 + r;

    *(uint2*)&Kw[lane * 4] = *(const uint2*)(Kall + e * 256 + lane * 4);

    const float* Tp = triplet + e * 1024 + n_l * 32 + hh * 8;
    FB a0f, a1f;
    {
      float4 t0 = *(const float4*)(Tp);
      float4 t1 = *(const float4*)(Tp + 4);
      a0f.u[0] = f2bf(t0.x); a0f.u[1] = f2bf(t0.y); a0f.u[2] = f2bf(t0.z); a0f.u[3] = f2bf(t0.w);
      a0f.u[4] = f2bf(t1.x); a0f.u[5] = f2bf(t1.y); a0f.u[6] = f2bf(t1.z); a0f.u[7] = f2bf(t1.w);
      float4 t2 = *(const float4*)(Tp + 16);
      float4 t3 = *(const float4*)(Tp + 20);
      a1f.u[0] = f2bf(t2.x); a1f.u[1] = f2bf(t2.y); a1f.u[2] = f2bf(t2.z); a1f.u[3] = f2bf(t2.w);
      a1f.u[4] = f2bf(t3.x); a1f.u[5] = f2bf(t3.y); a1f.u[6] = f2bf(t3.z); a1f.u[7] = f2bf(t3.w);
    }
    fx16 atq, atk;
#pragma unroll
    for (int j = 0; j < 16; ++j) { atq[j] = btqc; atk[j] = btkc; }
    atq = __builtin_amdgcn_mfma_f32_32x32x16_bf16(a0f.v, bqf[0].v, atq, 0, 0, 0);
    atq = __builtin_amdgcn_mfma_f32_32x32x16_bf16(a1f.v, bqf[1].v, atq, 0, 0, 0);
    atk = __builtin_amdgcn_mfma_f32_32x32x16_bf16(a0f.v, bkf[0].v, atk, 0, 0, 0);
    atk = __builtin_amdgcn_mfma_f32_32x32x16_bf16(a1f.v, bkf[1].v, atk, 0, 0, 0);

#pragma unroll
    for (int reg = 0; reg < 16; ++reg) {
      int n = (reg & 3) + 8 * (reg >> 2) + 4 * hh;
      tqw[n * 36 + n_l] = atq[reg];
      tkw[n * 36 + n_l] = atk[reg];
    }
    __builtin_amdgcn_wave_barrier();

    float sc[4] = {0.f, 0.f, 0.f, 0.f};
#pragma unroll
    for (int dp = 0; dp < 8; ++dp) {
      float4 tq4 = *(const float4*)&tqw[n_l * 36 + dp * 4];
      float4 tk4 = *(const float4*)&tkw[n_l * 36 + dp * 4];
#pragma unroll
      for (int u = 0; u < 4; ++u) {
        int h = u * 2 + hh;
        uint2 q4 = *(const uint2*)&qs[n_l * 260 + h * 32 + dp * 4];
        uint2 k4 = *(const uint2*)&Kw[h * 32 + dp * 4];
        float2 qa = bf2x(q4.x), qc = bf2x(q4.y);
        float2 ka = bf2x(k4.x), kc = bf2x(k4.y);
        sc[u] = fmaf(qa.x, ka.x + tq4.x, fmaf(ka.x, tk4.x, sc[u]));
        sc[u] = fmaf(qa.y, ka.y + tq4.y, fmaf(ka.y, tk4.y, sc[u]));
        sc[u] = fmaf(qc.x, kc.x + tq4.z, fmaf(kc.x, tk4.z, sc[u]));
        sc[u] = fmaf(qc.y, kc.y + tq4.w, fmaf(kc.y, tk4.w, sc[u]));
      }
    }

    const float mv = mask[e * 32 + n_l];
#pragma unroll
    for (int u = 0; u < 4; ++u) {
      float s = sc[u] * 0.17677669529663687f + mv;
      float mx = s;
#pragma unroll
      for (int m = 16; m >= 1; m >>= 1) mx = fmaxf(mx, __shfl_xor(mx, m, 64));
      float p = __expf(s - mx);
      float sum = p;
#pragma unroll
      for (int m = 16; m >= 1; m >>= 1) sum += __shfl_xor(sum, m, 64);
      pw[(u * 2 + hh) * 33 + n_l] = p / sum;
    }
    __builtin_amdgcn_wave_barrier();

    {
      float c0 = 0.f, c1 = 0.f, c2 = 0.f, c3 = 0.f;
      const float* prow = pw + hj * 33;
#pragma unroll 8
      for (int n = 0; n < 32; ++n) {
        float p = prow[n];
        uint2 vv = *(const uint2*)&vs[n * 256 + j0];
        float2 va = bf2x(vv.x), vbv = bf2x(vv.y);
        c0 = fmaf(p, va.x, c0); c1 = fmaf(p, va.y, c1);
        c2 = fmaf(p, vbv.x, c2); c3 = fmaf(p, vbv.y, c3);
      }
      ctxr[i][0] = (unsigned)f2bf(c0) | ((unsigned)f2bf(c1) << 16);
      ctxr[i][1] = (unsigned)f2bf(c2) | ((unsigned)f2bf(c3) << 16);
    }
  }
  __syncthreads();

  // phase 2a: ctx regs -> cxs (overlays tkb)
  unsigned short* cxs = (unsigned short*)(smem + 51456);  // [32][264]
#pragma unroll
  for (int i = 0; i < 8; ++i) {
    int r = w * 8 + i;
    uint2 st; st.x = ctxr[i][0]; st.y = ctxr[i][1];
    *(uint2*)&cxs[r * 264 + j0] = st;
  }
  __syncthreads();

  // phase 2b: x = ctx@Wo + bo + structure  (VALU fp32, round-1-proven layout)
  float* xb = (float*)smem;  // [32][260] f32, overlays qs/vs (+head of tqb)
  {
    const int rg = t >> 5, cg = t & 31;
    float acc[4][8];
#pragma unroll
    for (int a = 0; a < 4; ++a)
#pragma unroll
      for (int c = 0; c < 8; ++c) acc[a][c] = 0.f;
    const float* wb = Wo + cg * 8;
    for (int i4 = 0; i4 < 256; i4 += 4) {
      float cv[4][4];
#pragma unroll
      for (int a = 0; a < 4; ++a) {
        uint2 c2 = *(const uint2*)&cxs[(rg * 4 + a) * 264 + i4];
        float2 x0 = bf2x(c2.x), x1 = bf2x(c2.y);
        cv[a][0] = x0.x; cv[a][1] = x0.y; cv[a][2] = x1.x; cv[a][3] = x1.y;
      }
#pragma unroll
      for (int s = 0; s < 4; ++s) {
        float4 w0 = *(const float4*)(wb + (i4 + s) * 256);
        float4 w1 = *(const float4*)(wb + (i4 + s) * 256 + 4);
#pragma unroll
        for (int a = 0; a < 4; ++a) {
          float c = cv[a][s];
          acc[a][0] = fmaf(c, w0.x, acc[a][0]);
          acc[a][1] = fmaf(c, w0.y, acc[a][1]);
          acc[a][2] = fmaf(c, w0.z, acc[a][2]);
          acc[a][3] = fmaf(c, w0.w, acc[a][3]);
          acc[a][4] = fmaf(c, w1.x, acc[a][4]);
          acc[a][5] = fmaf(c, w1.y, acc[a][5]);
          acc[a][6] = fmaf(c, w1.z, acc[a][6]);
          acc[a][7] = fmaf(c, w1.w, acc[a][7]);
        }
      }
    }
    float4 bo0 = *(const float4*)(bo + cg * 8);
    float4 bo1 = *(const float4*)(bo + cg * 8 + 4);
#pragma unroll
    for (int a = 0; a < 4; ++a) {
      int row = rg * 4 + a;
      const float* sp = structure + ((size_t)bl * 32 + row) * 256 + cg * 8;
      float4 s0 = *(const float4*)sp;
      float4 s1 = *(const float4*)(sp + 4);
      float4 o0, o1;
      o0.x = acc[a][0] + bo0.x + s0.x;
      o0.y = acc[a][1] + bo0.y + s0.y;
      o0.z = acc[a][2] + bo0.z + s0.z;
      o0.w = acc[a][3] + bo0.w + s0.w;
      o1.x = acc[a][4] + bo1.x + s1.x;
      o1.y = acc[a][5] + bo1.y + s1.y;
      o1.z = acc[a][6] + bo1.z + s1.z;
      o1.w = acc[a][7] + bo1.w + s1.w;
      *(float4*)&xb[row * 260 + cg * 8]     = o0;
      *(float4*)&xb[row * 260 + cg * 8 + 4] = o1;
    }
  }
  __syncthreads();

  // phase 2c: LayerNorm, wave w -> rows w*8..w*8+7
#pragma unroll
  for (int rr = 0; rr < 8; ++rr) {
    int r = w * 8 + rr;
    float4 x4 = *(const float4*)&xb[r * 260 + lane * 4];
    float s1 = x4.x + x4.y + x4.z + x4.w;
    float s2 = fmaf(x4.x, x4.x, fmaf(x4.y, x4.y, fmaf(x4.z, x4.z, x4.w * x4.w)));
#pragma unroll
    for (int m = 32; m >= 1; m >>= 1) {
      s1 += __shfl_xor(s1, m, 64);
      s2 += __shfl_xor(s2, m, 64);
    }
    float mu = s1 * (1.f / 256.f);
    float var = s2 * (1.f / 256.f) - mu * mu;
    float rstd = rsqrtf(var + 1e-5f);
    float4 g = *(const float4*)(gamma + lane * 4);
    float4 bt = *(const float4*)(beta + lane * 4);
    float4 o;
    o.x = (x4.x - mu) * rstd * g.x + bt.x;
    o.y = (x4.y - mu) * rstd * g.y + bt.y;
    o.z = (x4.z - mu) * rstd * g.z + bt.z;
    o.w = (x4.w - mu) * rstd * g.w + bt.w;
    *(float4*)&out[((size_t)bl * 32 + r) * 256 + lane * 4] = o;
  }
}

extern "C" void kernel_launch(void* const* d_in, const int* in_sizes, int n_in,
                              void* d_out, int out_size, void* d_ws, size_t ws_size,
                              hipStream_t stream) {
  const float* hidden    = (const float*)d_in[0];
  const float* structure = (const float*)d_in[1];
  const float* triplet   = (const float*)d_in[2];
  const float* mask      = (const float*)d_in[3];
  const float* Wq  = (const float*)d_in[4];
  const float* bq  = (const float*)d_in[5];
  const float* Wk  = (const float*)d_in[6];
  const float* bk  = (const float*)d_in[7];
  const float* Wv  = (const float*)d_in[8];
  const float* bv  = (const float*)d_in[9];
  const float* Wo  = (const float*)d_in[10];
  const float* bo  = (const float*)d_in[11];
  const float* gamma = (const float*)d_in[12];
  const float* beta  = (const float*)d_in[13];
  const float* Wtq = (const float*)d_in[14];
  const float* btq = (const float*)d_in[15];
  const float* Wtk = (const float*)d_in[16];
  const float* btk = (const float*)d_in[17];
  float* out = (float*)d_out;

  unsigned short* qb   = (unsigned short*)d_ws;  // [1024][256]
  unsigned short* vbp  = qb + 262144;
  unsigned short* krb  = vbp + 262144;
  unsigned short* kcb  = krb + 262144;
  unsigned short* Wk3T = kcb + 262144;           // [256][256]
  unsigned short* Kall = Wk3T + 65536;           // [32768][256]
  // total: 9,502,720 u16 = 19.0 MB

  hipLaunchKernelGGL(k_prep, dim3(256), dim3(256), 0, stream, Wk, Wk3T);
  hipLaunchKernelGGL(k_small, dim3(256), dim3(256), 0, stream,
                     hidden, Wq, bq, Wk, Wv, bv, qb, vbp, krb, kcb);
  hipLaunchKernelGGL(k_kproj, dim3(1024), dim3(256), 0, stream,
                     structure, Wk3T, bk, krb, kcb, Kall);
  hipLaunchKernelGGL(k_attn, dim3(1024), dim3(256), 0, stream,
                     qb, vbp, Kall, triplet, mask, Wtq, btq, Wtk, btk,
                     Wo, bo, structure, gamma, beta, out);
}